// Round 13
// baseline (181.447 us; speedup 1.0000x reference)
//
#include <hip/hip_runtime.h>
#include <hip/hip_bf16.h>

typedef __attribute__((ext_vector_type(8))) short short8;
typedef __attribute__((ext_vector_type(4))) float f32x4;

#define HEADS 16
#define DH    64
#define LSEQ  512
#define CD    1024
#define MROWS 8192            /* B*T*L */

static __device__ __forceinline__ unsigned short f2bf(float f) {
    union { float f; unsigned int u; } v; v.f = f;
    unsigned int u = v.u;
    u += 0x7fffu + ((u >> 16) & 1u);   // round-to-nearest-even
    return (unsigned short)(u >> 16);
}

static __device__ __forceinline__ void gload16(const unsigned short* g, char* lds) {
    __builtin_amdgcn_global_load_lds(
        (const __attribute__((address_space(1))) void*)g,
        (__attribute__((address_space(3))) void*)lds, 16, 0, 0);
}

// ---------------- f32 -> bf16 bulk convert (vec4, row-major) ----------------
__global__ __launch_bounds__(256)
void cvt_kernel(const float* __restrict__ s, unsigned short* __restrict__ d, int n4) {
    union U { unsigned short us[4]; unsigned long long u; };
    for (int i = blockIdx.x * blockDim.x + threadIdx.x; i < n4; i += gridDim.x * blockDim.x) {
        const float4 v = ((const float4*)s)[i];
        U p; p.us[0] = f2bf(v.x); p.us[1] = f2bf(v.y); p.us[2] = f2bf(v.z); p.us[3] = f2bf(v.w);
        ((unsigned long long*)d)[i] = p.u;
    }
}

// ================== 8-phase 256x256 GEMM (faithful m201 port) ==============
// 8 waves (2M x 4N), BK=64, acc[8][4]. LDS 128KB: 2 slots x 4 quarter-regions
// {Aks0,Aks1,Bks0,Bks1} of 16KB. Quarter layout: 128 LDS rows x 128B; LDS row
// r holds logical rows r and r+128 (64B each), chunk XOR-swizzled by (r&7).
// Per iteration (2 K-tiles): 8 phases, each {ds_read 4-8 frags || stage 1
// half-tile (2 gloads) -> barrier -> lgkmcnt(0) -> 16 MFMA -> barrier}.
// Counted vmcnt(4) ONLY at phases 4 and 8 (stage->read distance = 6 phases).
#define AK0 0
#define AK1 16384
#define BK0 32768
#define BK1 49152
#define SLT 65536

#define STG_A(DST, KT, KS) do {                                              \
    gload16(Abase + (size_t)(KT) * 64 + (KS) * 32,           lds + (DST) + dst16); \
    gload16(Abase + 64 * CD + (size_t)(KT) * 64 + (KS) * 32, lds + (DST) + 8192 + dst16); \
} while (0)
#define STG_B(DST, KT, KS) do {                                              \
    gload16(Bbase + (size_t)(KT) * 64 + (KS) * 32,           lds + (DST) + dst16); \
    gload16(Bbase + 64 * CD + (size_t)(KT) * 64 + (KS) * 32, lds + (DST) + 8192 + dst16); \
} while (0)

#define PHASE(SB, KSOFF, MH, LOADB, STG_STMT, GATE) {                        \
    _Pragma("unroll")                                                        \
    for (int f = 0; f < 4; ++f)                                              \
        afr[f] = *(const short8*)(lds + (SB) + (KSOFF) + aoffL[MH][f]);      \
    if (LOADB) {                                                             \
        _Pragma("unroll")                                                    \
        for (int f = 0; f < 4; ++f)                                          \
            bfr[f] = *(const short8*)(lds + (SB) + (KSOFF) + 32768 + boffL[f]); \
    }                                                                        \
    STG_STMT;                                                                \
    __builtin_amdgcn_s_barrier();                                            \
    asm volatile("s_waitcnt lgkmcnt(0)" ::: "memory");                       \
    __builtin_amdgcn_sched_barrier(0);                                       \
    __builtin_amdgcn_s_setprio(1);                                           \
    _Pragma("unroll")                                                        \
    for (int ff = 0; ff < 4; ++ff)                                           \
        _Pragma("unroll")                                                    \
        for (int nf = 0; nf < 4; ++nf)                                       \
            acc[(MH) * 4 + ff][nf] = __builtin_amdgcn_mfma_f32_16x16x32_bf16(\
                afr[ff], bfr[nf], acc[(MH) * 4 + ff][nf], 0, 0, 0);          \
    __builtin_amdgcn_s_setprio(0);                                           \
    if (GATE) { asm volatile("s_waitcnt vmcnt(4)" ::: "memory");             \
                __builtin_amdgcn_sched_barrier(0); }                         \
    __builtin_amdgcn_s_barrier();                                            \
}

// ---------------- Kernel 1: fused QKV projection (8-phase 256^2) ----------
__global__ __launch_bounds__(512, 1)
void proj_qkv_kernel(const unsigned short* __restrict__ xb,
                     const unsigned short* __restrict__ wqkvb,
                     const float* __restrict__ bq, const float* __restrict__ bkv,
                     unsigned short* __restrict__ Qb, unsigned short* __restrict__ Kb,
                     unsigned short* __restrict__ Vtb)
{
    __shared__ __attribute__((aligned(16))) char lds[128 * 1024];

    // grid = 384 (32 m x 12 n of 256x256). XCD partition: 8m x 6n per XCD
    // -> B-panel 3MB L2-resident.
    const int xcd = blockIdx.x & 7, wgl = blockIdx.x >> 3;   // wgl 0..47
    const int im  = (xcd & 3) * 8 + wgl / 6;
    const int in  = (xcd >> 2) * 6 + wgl % 6;
    const int i0 = im * 256, j0 = in * 256;

    const int tid  = threadIdx.x;
    const int w    = tid >> 6;
    const int lane = tid & 63;
    const int colw = lane & 15;
    const int grp  = lane >> 4;
    const int wm   = w >> 2;          // 0..1 (M half: 128 rows)
    const int wn   = w & 3;           // 0..3 (N quarter: 64 cols)

    // staging constants: LDS row lr0 = tid>>3, phys chunk tid&7; logical
    // chunk cl = (tid&7)^(lr0&7); holds global row +128 if cl>=4, k-off (cl&3)*8
    const int lr0   = tid >> 3;
    const int clv   = (tid & 7) ^ (lr0 & 7);
    const int rsel  = clv >> 2;
    const int kcv   = (clv & 3) * 8;
    const int dst16 = tid * 16;
    const unsigned short* const Abase = xb    + (size_t)(i0 + lr0 + rsel * 128) * CD + kcv;
    const unsigned short* const Bbase = wqkvb + (size_t)(j0 + lr0 + rsel * 128) * CD + kcv;

    // frag ds_read byte offsets within a 16KB quarter-region
    int aoffL[2][4], boffL[4];
    #pragma unroll
    for (int mh = 0; mh < 2; ++mh)
        #pragma unroll
        for (int f = 0; f < 4; ++f)
            aoffL[mh][f] = ((mh * 4 + f) * 16 + colw) * 128 +
                           (((wm * 4 + grp) ^ (colw & 7)) << 4);
    #pragma unroll
    for (int f = 0; f < 4; ++f)
        boffL[f] = ((wn & 1) * 64 + f * 16 + colw) * 128 +
                   ((((wn >> 1) * 4 + grp) ^ (colw & 7)) << 4);

    f32x4 acc[8][4] = {};

    // ---- prologue: tile0 all 4 halves -> slot0; tile1 ks0 halves -> slot1 ----
    STG_A(AK0, 0, 0); STG_B(BK0, 0, 0); STG_A(AK1, 0, 1); STG_B(BK1, 0, 1);
    STG_A(SLT + AK0, 1, 0); STG_B(SLT + BK0, 1, 0);
    asm volatile("s_waitcnt vmcnt(4)" ::: "memory");
    __builtin_amdgcn_sched_barrier(0);
    __builtin_amdgcn_s_barrier();

    for (int it = 0; it < 8; ++it) {
        const int tO  = 2 * it + 1;
        const int tE2 = (2 * it + 2 < 16) ? 2 * it + 2 : 15;   // clamped restage
        const int tO2 = (2 * it + 3 < 16) ? 2 * it + 3 : 15;
        short8 afr[4], bfr[4];

        PHASE(0,   AK0, 0, 1, STG_A(SLT + AK1, tO,  1), 0)   // P1: s0 ks0 mh0 +B
        PHASE(0,   AK0, 1, 0, STG_B(SLT + BK1, tO,  1), 0)   // P2: s0 ks0 mh1
        PHASE(0,   AK1, 0, 1, STG_A(AK0,       tE2, 0), 0)   // P3: s0 ks1 mh0 +B
        PHASE(0,   AK1, 1, 0, STG_B(BK0,       tE2, 0), 1)   // P4: gate vmcnt(4)
        PHASE(SLT, AK0, 0, 1, STG_A(AK1,       tE2, 1), 0)   // P5: s1 ks0 mh0 +B
        PHASE(SLT, AK0, 1, 0, STG_B(BK1,       tE2, 1), 0)   // P6: s1 ks0 mh1
        PHASE(SLT, AK1, 0, 1, STG_A(SLT + AK0, tO2, 0), 0)   // P7: s1 ks1 mh0 +B
        PHASE(SLT, AK1, 1, 0, STG_B(SLT + BK0, tO2, 0), 1)   // P8: gate vmcnt(4)
    }

    // ---- epilogue: bias + l2norm over 64-col head; scatter store ----
    const int jbase = j0 + wn * 64;               // head-aligned, wave-uniform
    const float* bp = (jbase < CD) ? (bq + jbase) : (bkv + (jbase - CD));
    #pragma unroll
    for (int nf = 0; nf < 4; ++nf) {
        const float bv = bp[nf * 16 + colw];
        #pragma unroll
        for (int mf = 0; mf < 8; ++mf)
            #pragma unroll
            for (int r = 0; r < 4; ++r) acc[mf][nf][r] += bv;
    }
    const float qscale = (jbase < CD) ? 0.125f : 1.0f;
    unsigned short* dst; int jloc;
    if (jbase < CD)            { dst = Qb;  jloc = jbase; }
    else if (jbase < 2 * CD)   { dst = Kb;  jloc = jbase - CD; }
    else                       { dst = Vtb; jloc = jbase - 2 * CD; }
    const int h = jloc >> 6;
    #pragma unroll
    for (int mf = 0; mf < 8; ++mf) {
        #pragma unroll
        for (int r = 0; r < 4; ++r) {
            float t = 0.f;
            #pragma unroll
            for (int nf = 0; nf < 4; ++nf) t += acc[mf][nf][r] * acc[mf][nf][r];
            t += __shfl_xor(t, 1);
            t += __shfl_xor(t, 2);
            t += __shfl_xor(t, 4);
            t += __shfl_xor(t, 8);
            const float inv = qscale / fmaxf(sqrtf(t), 1e-12f);
            const int i  = i0 + wm * 128 + mf * 16 + grp * 4 + r;
            const int bt = i >> 9, li = i & 511;
            #pragma unroll
            for (int nf = 0; nf < 4; ++nf) {
                const int d = nf * 16 + colw;
                const unsigned short hv = f2bf(acc[mf][nf][r] * inv);
                if (jbase < 2 * CD)
                    dst[(((size_t)(bt * HEADS + h)) * LSEQ + li) * DH + d] = hv;     // Q or K [l][d]
                else
                    // V tiled: [bth][l/64][d][64] -> contiguous 8KB kv-tiles for attn
                    dst[((((size_t)(bt * HEADS + h)) * 8 + (li >> 6)) * DH + d) * 64 + (li & 63)] = hv;
            }
        }
    }
}

// ================= 2-phase double-buffered GEMM core (proj_out) =============
#define BUFB 32768   /* bytes per LDS buffer: A 16KB + B 16KB */

static __device__ __forceinline__ void gemm128_core(
    const unsigned short* __restrict__ Ap,
    const unsigned short* __restrict__ Bp,
    int i0, int n0, char* lds, f32x4 acc[4][4])
{
    const int tid  = threadIdx.x;
    const int wv   = tid >> 6;
    const int lane = tid & 63;
    const int colw = lane & 15;
    const int grp  = lane >> 4;
    const int wr   = wv >> 1;
    const int wc   = wv & 1;

    const int srow0 = lane >> 3;
    const int sclog = (lane & 7) ^ (srow0 & 7);
    const int adst  = wv * 32 * 128;
    const int bdst  = 16384 + wv * 32 * 128;

    int aoff[2][4], boff[2][4];
    #pragma unroll
    for (int ks = 0; ks < 2; ++ks) {
        #pragma unroll
        for (int f = 0; f < 4; ++f) {
            const int ra = wr * 64 + f * 16 + colw;
            const int rb = wc * 64 + f * 16 + colw;
            aoff[ks][f] = ra * 128 + (((ks * 4 + grp) ^ (ra & 7)) << 4);
            boff[ks][f] = 16384 + rb * 128 + (((ks * 4 + grp) ^ (rb & 7)) << 4);
        }
    }

    const int NT = CD / 64;

    #pragma unroll
    for (int c = 0; c < 4; ++c) {
        const int row = wv * 32 + c * 8 + srow0;
        gload16(Ap + (size_t)(i0 + row) * CD + sclog * 8, lds + adst + c * 1024);
        gload16(Bp + (size_t)(n0 + row) * CD + sclog * 8, lds + bdst + c * 1024);
    }
    asm volatile("s_waitcnt vmcnt(0)" ::: "memory");
    __builtin_amdgcn_s_barrier();

    for (int t = 0; t < NT; ++t) {
        char* const cb = lds + (t & 1) * BUFB;
        char* const nb = lds + ((t & 1) ^ 1) * BUFB;

        if (t + 1 < NT) {
            const int kt = (t + 1) * 64;
            #pragma unroll
            for (int c = 0; c < 4; ++c) {
                const int row = wv * 32 + c * 8 + srow0;
                gload16(Ap + (size_t)(i0 + row) * CD + kt + sclog * 8, nb + adst + c * 1024);
                gload16(Bp + (size_t)(n0 + row) * CD + kt + sclog * 8, nb + bdst + c * 1024);
            }
        }
        short8 af[2][4], bf[2][4];
        #pragma unroll
        for (int ks = 0; ks < 2; ++ks) {
            #pragma unroll
            for (int f = 0; f < 4; ++f) {
                af[ks][f] = *(const short8*)(cb + aoff[ks][f]);
                bf[ks][f] = *(const short8*)(cb + boff[ks][f]);
            }
        }
        __builtin_amdgcn_s_setprio(1);
        #pragma unroll
        for (int ks = 0; ks < 2; ++ks)
            #pragma unroll
            for (int mf = 0; mf < 4; ++mf)
                #pragma unroll
                for (int nf = 0; nf < 4; ++nf)
                    acc[mf][nf] = __builtin_amdgcn_mfma_f32_16x16x32_bf16(af[ks][mf], bf[ks][nf], acc[mf][nf], 0, 0, 0);
        __builtin_amdgcn_s_setprio(0);

        asm volatile("s_waitcnt vmcnt(0)" ::: "memory");
        __builtin_amdgcn_s_barrier();
    }
}

// ---------------- Kernel 2: flash attention per (b,t,h) ----------
// Bounded-score softmax (|s|<=0.125): exp(s) directly, no max tracking.
__global__ __launch_bounds__(512)
void attn_kernel(const unsigned short* __restrict__ Qb,
                 const unsigned short* __restrict__ Kb,
                 const unsigned short* __restrict__ Vtb,   // tiled [bth][8][64][64]
                 unsigned short* __restrict__ Ob)
{
    __shared__ __attribute__((aligned(16))) unsigned short Ksm[64 * 64];
    __shared__ __attribute__((aligned(16))) unsigned short Vsm[64 * 64];
    __shared__ __attribute__((aligned(16))) unsigned short Psm[8][16 * 72];

    const int tid  = threadIdx.x;
    const int w    = tid >> 6;        // 0..7
    const int lane = tid & 63;
    const int colw = lane & 15;
    const int grp  = lane >> 4;

    const int bth = blockIdx.x & 255;     // head id (same XCD for all its q-tiles)
    const int qt  = blockIdx.x >> 8;      // 0..3
    const int q0  = qt * 128 + w * 16;    // wave's first q row

    const unsigned short* Qh = Qb  + (size_t)bth * LSEQ * DH;
    const unsigned short* Kh = Kb  + (size_t)bth * LSEQ * DH;
    const unsigned short* Vh = Vtb + (size_t)bth * LSEQ * DH;  // tiled

    short8 aq[2];
    #pragma unroll
    for (int ks = 0; ks < 2; ++ks)
        aq[ks] = *(const short8*)&Qh[(size_t)(q0 + colw) * DH + ks * 32 + grp * 8];

    const int srow   = w * 8 + (lane >> 3);          // 0..63
    const int schunk = (lane & 7) ^ (srow & 7);      // swizzled 16B chunk
    const int goff   = srow * DH + schunk * 8;       // element offset in 8KB tile
    char* const kdst = (char*)Ksm + w * 1024;
    char* const vdst = (char*)Vsm + w * 1024;

    float plsum[4] = {0.f, 0.f, 0.f, 0.f};
    f32x4 oacc[4] = {};

    for (int t = 0; t < 8; ++t) {
        gload16(Kh + t * 4096 + goff, kdst);
        gload16(Vh + t * 4096 + goff, vdst);
        __syncthreads();                 // drains vmcnt -> tiles ready

        f32x4 s[4] = {};
        #pragma unroll
        for (int ks = 0; ks < 2; ++ks) {
            #pragma unroll
            for (int nf = 0; nf < 4; ++nf) {
                const int rowb = nf * 16 + colw;
                const short8 bk = *(const short8*)((char*)Ksm + rowb * 128 +
                                       ((((ks * 4 + grp) ^ (rowb & 7))) << 4));
                s[nf] = __builtin_amdgcn_mfma_f32_16x16x32_bf16(aq[ks], bk, s[nf], 0, 0, 0);
            }
        }
        #pragma unroll
        for (int nf = 0; nf < 4; ++nf) {
            #pragma unroll
            for (int r = 0; r < 4; ++r) {
                const float p = __expf(s[nf][r]);
                plsum[r] += p;
                Psm[w][(grp * 4 + r) * 72 + nf * 16 + colw] = f2bf(p);
            }
        }
        #pragma unroll
        for (int ks2 = 0; ks2 < 2; ++ks2) {
            const short8 ap = *(const short8*)&Psm[w][colw * 72 + ks2 * 32 + grp * 8];
            #pragma unroll
            for (int nf = 0; nf < 4; ++nf) {
                const int rowv = nf * 16 + colw;
                const short8 bv = *(const short8*)((char*)Vsm + rowv * 128 +
                                       ((((ks2 * 4 + grp) ^ (rowv & 7))) << 4));
                oacc[nf] = __builtin_amdgcn_mfma_f32_16x16x32_bf16(ap, bv, oacc[nf], 0, 0, 0);
            }
        }
        __syncthreads();                 // protect LDS tiles before restage
    }

    float oinv[4];
    #pragma unroll
    for (int r = 0; r < 4; ++r) {
        float t = plsum[r];
        t += __shfl_xor(t, 1);
        t += __shfl_xor(t, 2);
        t += __shfl_xor(t, 4);
        t += __shfl_xor(t, 8);
        oinv[r] = 1.0f / t;
    }

    const int bt = bth >> 4, h = bth & 15;
    #pragma unroll
    for (int nf = 0; nf < 4; ++nf) {
        #pragma unroll
        for (int r = 0; r < 4; ++r) {
            const int i = bt * LSEQ + q0 + grp * 4 + r;
            const int c = h * 64 + nf * 16 + colw;
            Ob[(size_t)i * CD + c] = f2bf(oacc[nf][r] * oinv[r]);
        }
    }
}

// ---------------- Kernel 3: output projection + bias + residual ----------
__global__ __launch_bounds__(256, 2)
void proj_out_kernel(const unsigned short* __restrict__ Ob,
                     const unsigned short* __restrict__ wmb,
                     const float* __restrict__ bm,
                     const float* __restrict__ x, float* __restrict__ out)
{
    __shared__ __attribute__((aligned(16))) char lds[64 * 1024];

    // grid = 512. XCD partition: 16m x 4n rectangle per XCD.
    const int xcd = blockIdx.x & 7, wgl = blockIdx.x >> 3;   // wgl 0..63
    const int im  = (xcd & 3) * 16 + (wgl >> 2);
    const int in  = (xcd >> 2) * 4 + (wgl & 3);
    const int i0 = im * 128, j0 = in * 128;

    const int tid  = threadIdx.x;
    const int wv   = tid >> 6;
    const int lane = tid & 63;
    const int colw = lane & 15;
    const int grp  = lane >> 4;
    const int wr   = wv >> 1, wc = wv & 1;

    f32x4 acc[4][4] = {};
    gemm128_core(Ob, wmb, i0, j0, lds, acc);

    #pragma unroll
    for (int nf = 0; nf < 4; ++nf) {
        const int j = j0 + wc * 64 + nf * 16 + colw;
        const float bv = bm[j];
        #pragma unroll
        for (int mf = 0; mf < 4; ++mf) {
            #pragma unroll
            for (int r = 0; r < 4; ++r) {
                const int i = i0 + wr * 64 + mf * 16 + grp * 4 + r;
                out[(size_t)i * CD + j] = acc[mf][nf][r] + bv + x[(size_t)i * CD + j];
            }
        }
    }
}

extern "C" void kernel_launch(void* const* d_in, const int* in_sizes, int n_in,
                              void* d_out, int out_size, void* d_ws, size_t ws_size,
                              hipStream_t stream) {
    const float* x   = (const float*)d_in[0];
    const float* wq  = (const float*)d_in[1];
    const float* bq  = (const float*)d_in[2];
    const float* wkv = (const float*)d_in[3];
    const float* bkv = (const float*)d_in[4];
    const float* wm  = (const float*)d_in[5];
    const float* bm  = (const float*)d_in[6];
    float* out = (float*)d_out;

    // ws layout (64 MB, timeline-aliased):
    //  R0: xb (convert->proj_qkv), then Ob (attn->proj_out)
    //  R1: Qb (proj_qkv->attn), then wmb (cvt-after-attn->proj_out)
    //  R2: Kb   R3: Vtb
    // wqkvb lives in d_out (dead before proj_out writes it).
    const size_t SEG = (size_t)MROWS * CD;
    unsigned short* xb    = (unsigned short*)d_ws;
    unsigned short* Ob    = xb;
    unsigned short* Qb    = xb + SEG;
    unsigned short* wmb   = Qb;
    unsigned short* Kb    = Qb + SEG;
    unsigned short* Vtb   = Kb + SEG;
    unsigned short* wqkvb = (unsigned short*)d_out;

    cvt_kernel<<<2048, 256, 0, stream>>>(x,   xb,    (MROWS * CD) / 4);
    cvt_kernel<<<1024, 256, 0, stream>>>(wq,  wqkvb, (CD * CD) / 4);
    cvt_kernel<<<1024, 256, 0, stream>>>(wkv, wqkvb + (size_t)CD * CD, (2 * CD * CD) / 4);
    proj_qkv_kernel<<<384, 512, 0, stream>>>(xb, wqkvb, bq, bkv, Qb, Kb, Vtb);
    attn_kernel<<<1024, 512, 0, stream>>>(Qb, Kb, Vtb, Ob);
    cvt_kernel<<<1024, 256, 0, stream>>>(wm, wmb, (CD * CD) / 4);
    proj_out_kernel<<<512, 256, 0, stream>>>(Ob, wmb, bm, x, out);
}

// Round 14
// 141.703 us; speedup vs baseline: 1.2805x; 1.2805x over previous
//
#include <hip/hip_runtime.h>
#include <hip/hip_bf16.h>

typedef __attribute__((ext_vector_type(8))) short short8;
typedef __attribute__((ext_vector_type(4))) float f32x4;

#define HEADS 16
#define DH    64
#define LSEQ  512
#define CD    1024
#define MROWS 8192            /* B*T*L */

static __device__ __forceinline__ unsigned short f2bf(float f) {
    union { float f; unsigned int u; } v; v.f = f;
    unsigned int u = v.u;
    u += 0x7fffu + ((u >> 16) & 1u);   // round-to-nearest-even
    return (unsigned short)(u >> 16);
}

// pack 4 floats -> 4 fp8 e4m3 bytes (OCP, HW convert)
static __device__ __forceinline__ unsigned int pk4_fp8(float a, float b, float c, float d) {
    int v = __builtin_amdgcn_cvt_pk_fp8_f32(a, b, 0, false);   // bytes 0,1
    v = __builtin_amdgcn_cvt_pk_fp8_f32(c, d, v, true);        // bytes 2,3
    return (unsigned int)v;
}
static __device__ __forceinline__ unsigned char f2fp8(float a) {
    return (unsigned char)(__builtin_amdgcn_cvt_pk_fp8_f32(a, a, 0, false) & 0xff);
}

static __device__ __forceinline__ void gload16(const void* g, char* lds) {
    __builtin_amdgcn_global_load_lds(
        (const __attribute__((address_space(1))) void*)g,
        (__attribute__((address_space(3))) void*)lds, 16, 0, 0);
}

// ---------------- f32 -> fp8 e4m3 bulk convert (8 elems/thread) -------------
__global__ __launch_bounds__(256)
void cvt_fp8_kernel(const float* __restrict__ s, unsigned char* __restrict__ d, int n8) {
    for (int i = blockIdx.x * blockDim.x + threadIdx.x; i < n8; i += gridDim.x * blockDim.x) {
        const float4 v0 = ((const float4*)s)[2 * i];
        const float4 v1 = ((const float4*)s)[2 * i + 1];
        uint2 p;
        p.x = pk4_fp8(v0.x, v0.y, v0.z, v0.w);
        p.y = pk4_fp8(v1.x, v1.y, v1.z, v1.w);
        ((uint2*)d)[i] = p;
    }
}

// ========== 2-phase dbuf GEMM core, FP8 inputs, BK=128 (8 K-steps) ==========
// BM=BN=128, 4 waves (2x2), 2 x 32KB LDS dbuf (64KB -> 2 blk/CU), ONE raw
// barrier per K-tile (round-9 schedule: stage-first, vmcnt(0)+barrier).
// fp8 halves bytes/K -> BK=128 at the SAME LDS/staging cost as bf16 BK=64,
// halving the number of latency-dominated K-steps (the measured cost driver).
// T2 both-sides XOR 16B-chunk swizzle; frag reads are 8B (b64).
static __device__ __forceinline__ void gemm128_fp8_core(
    const unsigned char* __restrict__ Ap,   // [M][1024] fp8 row-major
    const unsigned char* __restrict__ Bp,   // [N][1024] fp8 row-major
    int i0, int n0, char* lds, f32x4 acc[4][4])
{
    const int tid  = threadIdx.x;
    const int wv   = tid >> 6;        // 0..3
    const int lane = tid & 63;
    const int colw = lane & 15;
    const int grp  = lane >> 4;
    const int wr   = wv >> 1;         // row half
    const int wc   = wv & 1;          // col half

    // staging: per instr, wave covers 8 rows x 128B (dense); LDS dest linear.
    const int srow0 = lane >> 3;                 // 0..7 row within 8-row chunk
    const int sclog = (lane & 7) ^ (srow0 & 7);  // pre-swizzled global 16B chunk
    const int adst  = wv * 32 * 128;             // A: 0..16K
    const int bdst  = 16384 + wv * 32 * 128;     // B: 16K..32K

    // frag ds_read byte offsets: row*128 + ((ks*2+(grp>>1))^(row&7))*16 + (grp&1)*8
    int aoff[4][4], boff[4][4];
    #pragma unroll
    for (int ks = 0; ks < 4; ++ks) {
        #pragma unroll
        for (int f = 0; f < 4; ++f) {
            const int ra = wr * 64 + f * 16 + colw;
            const int rb = wc * 64 + f * 16 + colw;
            const int ch = ks * 2 + (grp >> 1);
            aoff[ks][f] = ra * 128 + ((ch ^ (ra & 7)) << 4) + (grp & 1) * 8;
            boff[ks][f] = 16384 + rb * 128 + ((ch ^ (rb & 7)) << 4) + (grp & 1) * 8;
        }
    }

    const int NT = CD / 128;   // 8 K-tiles

    // ---- prologue: stage tile 0 into buf0, full drain once ----
    #pragma unroll
    for (int c = 0; c < 4; ++c) {
        const int row = wv * 32 + c * 8 + srow0;
        gload16(Ap + (size_t)(i0 + row) * CD + sclog * 16, lds + adst + c * 1024);
        gload16(Bp + (size_t)(n0 + row) * CD + sclog * 16, lds + bdst + c * 1024);
    }
    asm volatile("s_waitcnt vmcnt(0)" ::: "memory");
    __builtin_amdgcn_s_barrier();

    for (int t = 0; t < NT; ++t) {
        char* const cb = lds + (t & 1) * 32768;         // current buf (ready)
        char* const nb = lds + ((t & 1) ^ 1) * 32768;   // next buf (staging)

        // stage next tile FIRST (max flight time under this step)
        if (t + 1 < NT) {
            const int kt = (t + 1) * 128;
            #pragma unroll
            for (int c = 0; c < 4; ++c) {
                const int row = wv * 32 + c * 8 + srow0;
                gload16(Ap + (size_t)(i0 + row) * CD + kt + sclog * 16, nb + adst + c * 1024);
                gload16(Bp + (size_t)(n0 + row) * CD + kt + sclog * 16, nb + bdst + c * 1024);
            }
        }
        long long af[4][4], bf[4][4];
        #pragma unroll
        for (int ks = 0; ks < 4; ++ks) {
            #pragma unroll
            for (int f = 0; f < 4; ++f) {
                af[ks][f] = *(const long long*)(cb + aoff[ks][f]);
                bf[ks][f] = *(const long long*)(cb + boff[ks][f]);
            }
        }
        __builtin_amdgcn_s_setprio(1);
        #pragma unroll
        for (int ks = 0; ks < 4; ++ks)
            #pragma unroll
            for (int mf = 0; mf < 4; ++mf)
                #pragma unroll
                for (int nf = 0; nf < 4; ++nf)
                    acc[mf][nf] = __builtin_amdgcn_mfma_f32_16x16x32_fp8_fp8(
                        af[ks][mf], bf[ks][nf], acc[mf][nf], 0, 0, 0);
        __builtin_amdgcn_s_setprio(0);

        asm volatile("s_waitcnt vmcnt(0)" ::: "memory");
        __builtin_amdgcn_s_barrier();
    }
}

// ---------------- Kernel 1: fused QKV projection (fp8 in, bf16 out) --------
__global__ __launch_bounds__(256, 2)
void proj_qkv_kernel(const unsigned char* __restrict__ x8,
                     const unsigned char* __restrict__ w8,
                     const float* __restrict__ bq, const float* __restrict__ bkv,
                     unsigned short* __restrict__ Qb, unsigned short* __restrict__ Kb,
                     unsigned short* __restrict__ Vtb)
{
    __shared__ __attribute__((aligned(16))) char lds[64 * 1024];

    // grid = 1536. XCD partition: 16m x 12n per XCD -> B-panel 1.5MB L2-resident.
    const int xcd = blockIdx.x & 7, wgl = blockIdx.x >> 3;   // wgl 0..191
    const int im  = (xcd & 3) * 16 + wgl / 12;
    const int in  = (xcd >> 2) * 12 + wgl % 12;
    const int i0 = im * 128, j0 = in * 128;

    const int tid  = threadIdx.x;
    const int wv   = tid >> 6;
    const int lane = tid & 63;
    const int colw = lane & 15;
    const int grp  = lane >> 4;
    const int wr   = wv >> 1, wc = wv & 1;

    f32x4 acc[4][4] = {};
    gemm128_fp8_core(x8, w8, i0, j0, lds, acc);

    // ---- epilogue: bias + l2norm over 64-col head; scatter store ----
    const int jbase = j0 + wc * 64;               // head-aligned, wave-uniform
    const float* bp = (jbase < CD) ? (bq + jbase) : (bkv + (jbase - CD));
    #pragma unroll
    for (int nf = 0; nf < 4; ++nf) {
        const float bv = bp[nf * 16 + colw];
        #pragma unroll
        for (int mf = 0; mf < 4; ++mf)
            #pragma unroll
            for (int r = 0; r < 4; ++r) acc[mf][nf][r] += bv;
    }
    const float qscale = (jbase < CD) ? 0.125f : 1.0f;
    float inv[4][4];
    #pragma unroll
    for (int mf = 0; mf < 4; ++mf) {
        #pragma unroll
        for (int r = 0; r < 4; ++r) {
            float t = 0.f;
            #pragma unroll
            for (int nf = 0; nf < 4; ++nf) t += acc[mf][nf][r] * acc[mf][nf][r];
            t += __shfl_xor(t, 1);
            t += __shfl_xor(t, 2);
            t += __shfl_xor(t, 4);
            t += __shfl_xor(t, 8);
            inv[mf][r] = qscale / fmaxf(sqrtf(t), 1e-12f);
        }
    }
    unsigned short* dst; int jloc;
    if (jbase < CD)            { dst = Qb;  jloc = jbase; }
    else if (jbase < 2 * CD)   { dst = Kb;  jloc = jbase - CD; }
    else                       { dst = Vtb; jloc = jbase - 2 * CD; }
    const int h = jloc >> 6;
    #pragma unroll
    for (int mf = 0; mf < 4; ++mf) {
        #pragma unroll
        for (int nf = 0; nf < 4; ++nf) {
            const int d = nf * 16 + colw;
            #pragma unroll
            for (int r = 0; r < 4; ++r) {
                const int i  = i0 + wr * 64 + mf * 16 + grp * 4 + r;
                const int bt = i >> 9, li = i & 511;
                const unsigned short hv = f2bf(acc[mf][nf][r] * inv[mf][r]);
                if (jbase < 2 * CD)
                    dst[(((size_t)(bt * HEADS + h)) * LSEQ + li) * DH + d] = hv;     // Q or K [l][d]
                else
                    // V tiled: [bth][l/64][d][64] -> contiguous 8KB kv-tiles for attn
                    dst[((((size_t)(bt * HEADS + h)) * 8 + (li >> 6)) * DH + d) * 64 + (li & 63)] = hv;
            }
        }
    }
}

// ---------------- Kernel 2: flash attention per (b,t,h) ----------
// Bounded-score softmax (|s|<=0.125): exp(s) directly, no max tracking.
// O written as fp8 e4m3 (feeds the fp8 out-projection directly).
__global__ __launch_bounds__(512)
void attn_kernel(const unsigned short* __restrict__ Qb,
                 const unsigned short* __restrict__ Kb,
                 const unsigned short* __restrict__ Vtb,   // tiled [bth][8][64][64]
                 unsigned char* __restrict__ Ob)
{
    __shared__ __attribute__((aligned(16))) unsigned short Ksm[64 * 64];
    __shared__ __attribute__((aligned(16))) unsigned short Vsm[64 * 64];
    __shared__ __attribute__((aligned(16))) unsigned short Psm[8][16 * 72];

    const int tid  = threadIdx.x;
    const int w    = tid >> 6;        // 0..7
    const int lane = tid & 63;
    const int colw = lane & 15;
    const int grp  = lane >> 4;

    const int bth = blockIdx.x & 255;     // head id (same XCD for all its q-tiles)
    const int qt  = blockIdx.x >> 8;      // 0..3
    const int q0  = qt * 128 + w * 16;    // wave's first q row

    const unsigned short* Qh = Qb  + (size_t)bth * LSEQ * DH;
    const unsigned short* Kh = Kb  + (size_t)bth * LSEQ * DH;
    const unsigned short* Vh = Vtb + (size_t)bth * LSEQ * DH;  // tiled

    short8 aq[2];
    #pragma unroll
    for (int ks = 0; ks < 2; ++ks)
        aq[ks] = *(const short8*)&Qh[(size_t)(q0 + colw) * DH + ks * 32 + grp * 8];

    const int srow   = w * 8 + (lane >> 3);          // 0..63
    const int schunk = (lane & 7) ^ (srow & 7);      // swizzled 16B chunk
    const int goff   = srow * DH + schunk * 8;       // element offset in 8KB tile
    char* const kdst = (char*)Ksm + w * 1024;
    char* const vdst = (char*)Vsm + w * 1024;

    float plsum[4] = {0.f, 0.f, 0.f, 0.f};
    f32x4 oacc[4] = {};

    for (int t = 0; t < 8; ++t) {
        gload16(Kh + t * 4096 + goff, kdst);
        gload16(Vh + t * 4096 + goff, vdst);
        __syncthreads();                 // drains vmcnt -> tiles ready

        f32x4 s[4] = {};
        #pragma unroll
        for (int ks = 0; ks < 2; ++ks) {
            #pragma unroll
            for (int nf = 0; nf < 4; ++nf) {
                const int rowb = nf * 16 + colw;
                const short8 bk = *(const short8*)((char*)Ksm + rowb * 128 +
                                       ((((ks * 4 + grp) ^ (rowb & 7))) << 4));
                s[nf] = __builtin_amdgcn_mfma_f32_16x16x32_bf16(aq[ks], bk, s[nf], 0, 0, 0);
            }
        }
        #pragma unroll
        for (int nf = 0; nf < 4; ++nf) {
            #pragma unroll
            for (int r = 0; r < 4; ++r) {
                const float p = __expf(s[nf][r]);
                plsum[r] += p;
                Psm[w][(grp * 4 + r) * 72 + nf * 16 + colw] = f2bf(p);
            }
        }
        #pragma unroll
        for (int ks2 = 0; ks2 < 2; ++ks2) {
            const short8 ap = *(const short8*)&Psm[w][colw * 72 + ks2 * 32 + grp * 8];
            #pragma unroll
            for (int nf = 0; nf < 4; ++nf) {
                const int rowv = nf * 16 + colw;
                const short8 bv = *(const short8*)((char*)Vsm + rowv * 128 +
                                       ((((ks2 * 4 + grp) ^ (rowv & 7))) << 4));
                oacc[nf] = __builtin_amdgcn_mfma_f32_16x16x32_bf16(ap, bv, oacc[nf], 0, 0, 0);
            }
        }
        __syncthreads();                 // protect LDS tiles before restage
    }

    float oinv[4];
    #pragma unroll
    for (int r = 0; r < 4; ++r) {
        float t = plsum[r];
        t += __shfl_xor(t, 1);
        t += __shfl_xor(t, 2);
        t += __shfl_xor(t, 4);
        t += __shfl_xor(t, 8);
        oinv[r] = 1.0f / t;
    }

    const int bt = bth >> 4, h = bth & 15;
    #pragma unroll
    for (int nf = 0; nf < 4; ++nf) {
        #pragma unroll
        for (int r = 0; r < 4; ++r) {
            const int i = bt * LSEQ + q0 + grp * 4 + r;
            const int c = h * 64 + nf * 16 + colw;
            Ob[(size_t)i * CD + c] = f2fp8(oacc[nf][r] * oinv[r]);
        }
    }
}

// ---------------- Kernel 3: output projection + bias + residual ----------
__global__ __launch_bounds__(256, 2)
void proj_out_kernel(const unsigned char* __restrict__ O8,
                     const unsigned char* __restrict__ wm8,
                     const float* __restrict__ bm,
                     const float* __restrict__ x, float* __restrict__ out)
{
    __shared__ __attribute__((aligned(16))) char lds[64 * 1024];

    // grid = 512. XCD partition: 16m x 4n rectangle per XCD.
    const int xcd = blockIdx.x & 7, wgl = blockIdx.x >> 3;   // wgl 0..63
    const int im  = (xcd & 3) * 16 + (wgl >> 2);
    const int in  = (xcd >> 2) * 4 + (wgl & 3);
    const int i0 = im * 128, j0 = in * 128;

    const int tid  = threadIdx.x;
    const int wv   = tid >> 6;
    const int lane = tid & 63;
    const int colw = lane & 15;
    const int grp  = lane >> 4;
    const int wr   = wv >> 1, wc = wv & 1;

    f32x4 acc[4][4] = {};
    gemm128_fp8_core(O8, wm8, i0, j0, lds, acc);

    #pragma unroll
    for (int nf = 0; nf < 4; ++nf) {
        const int j = j0 + wc * 64 + nf * 16 + colw;
        const float bv = bm[j];
        #pragma unroll
        for (int mf = 0; mf < 4; ++mf) {
            #pragma unroll
            for (int r = 0; r < 4; ++r) {
                const int i = i0 + wr * 64 + mf * 16 + grp * 4 + r;
                out[(size_t)i * CD + j] = acc[mf][nf][r] + bv + x[(size_t)i * CD + j];
            }
        }
    }
}

extern "C" void kernel_launch(void* const* d_in, const int* in_sizes, int n_in,
                              void* d_out, int out_size, void* d_ws, size_t ws_size,
                              hipStream_t stream) {
    const float* x   = (const float*)d_in[0];
    const float* wq  = (const float*)d_in[1];
    const float* bq  = (const float*)d_in[2];
    const float* wkv = (const float*)d_in[3];
    const float* bkv = (const float*)d_in[4];
    const float* wm  = (const float*)d_in[5];
    const float* bm  = (const float*)d_in[6];
    float* out = (float*)d_out;

    // ws layout (64 MB, timeline-aliased, byte offsets):
    //  [0,16M):  x8 fp8 (cvt->proj_qkv), then O8 fp8 (attn->proj_out)
    //  [16M,32M): Qb bf16 (proj_qkv->attn), then wm8 fp8 (cvt-after-attn->proj_out)
    //  [32M,48M): Kb bf16   [48M,64M): Vtb bf16
    // wqkv8 fp8 (3MB) lives in d_out (dead before proj_out writes it).
    char* base = (char*)d_ws;
    const size_t SEG = (size_t)MROWS * CD;           // elems per [8192][1024] plane
    unsigned char*  x8    = (unsigned char*)base;
    unsigned char*  O8    = (unsigned char*)base;    // alias (x8 dead after proj_qkv)
    unsigned short* Qb    = (unsigned short*)(base + 16 * 1024 * 1024);
    unsigned char*  wm8   = (unsigned char*)(base + 16 * 1024 * 1024);  // alias after attn
    unsigned short* Kb    = (unsigned short*)(base + 32 * 1024 * 1024);
    unsigned short* Vtb   = (unsigned short*)(base + 48 * 1024 * 1024);
    unsigned char*  wqkv8 = (unsigned char*)d_out;

    cvt_fp8_kernel<<<2048, 256, 0, stream>>>(x,   x8,    (MROWS * CD) / 8);
    cvt_fp8_kernel<<<512,  256, 0, stream>>>(wq,  wqkv8, (CD * CD) / 8);
    cvt_fp8_kernel<<<1024, 256, 0, stream>>>(wkv, wqkv8 + (size_t)CD * CD, (2 * CD * CD) / 8);
    proj_qkv_kernel<<<1536, 256, 0, stream>>>(x8, wqkv8, bq, bkv, Qb, Kb, Vtb);
    attn_kernel<<<1024, 512, 0, stream>>>(Qb, Kb, Vtb, O8);
    cvt_fp8_kernel<<<512, 256, 0, stream>>>(wm, wm8, (CD * CD) / 8);
    proj_out_kernel<<<512, 256, 0, stream>>>(O8, wm8, bm, x, out);
}